// Round 1
// baseline (621.903 us; speedup 1.0000x reference)
//
#include <hip/hip_runtime.h>
#include <hip/hip_bf16.h>

// AttentionPITF: B=16384, K=256, M=50 history tags.
// Strategy: tag_h depends only on tag id -> precompute tagH[50000,256] once
// (kernel A), then per-row attention with gathers (kernel B), then batched
// mix GEMM fused with the final dot (kernel C, atomicAdd into r).

#define KDIM 256
#define MHIST 50
#define XROW 54

// ---------------- Kernel A: tagH = relu(tagU @ W_att^T + b_att) ------------
// GEMM M=NT(50000), N=256, K=256, both operands row-major with contiguous K
// (NT layout). 64x64 tile, BK=32, 256 threads, 4x4 micro-tile per thread.
__global__ __launch_bounds__(256) void tagh_kernel(
    const float* __restrict__ tagU,   // [NT,256]
    const float* __restrict__ Watt,   // [256,256]
    const float* __restrict__ batt,   // [256]
    float* __restrict__ tagH,         // [NT,256]
    int NT)
{
    __shared__ float As[64][36];
    __shared__ float Bs[64][36];
    const int tid = threadIdx.x;
    const int tx = tid & 15, ty = tid >> 4;
    const int m0 = blockIdx.x * 64;
    const int n0 = blockIdx.y * 64;

    float acc[4][4] = {};

    for (int k0 = 0; k0 < KDIM; k0 += 32) {
        // stage A (64 rows x 32 k) and B (64 rows x 32 k): 512 float4 each pass
#pragma unroll
        for (int p = 0; p < 2; ++p) {
            const int r = (tid >> 3) + p * 32;
            const int c = (tid & 7) * 4;
            const int gm = m0 + r;
            float4 av = make_float4(0.f, 0.f, 0.f, 0.f);
            if (gm < NT) av = *(const float4*)&tagU[(size_t)gm * KDIM + k0 + c];
            *(float4*)&As[r][c] = av;
            const int gn = n0 + r;   // always < 256
            *(float4*)&Bs[r][c] = *(const float4*)&Watt[(size_t)gn * KDIM + k0 + c];
        }
        __syncthreads();
#pragma unroll
        for (int kk = 0; kk < 32; kk += 4) {
            float4 a[4], b[4];
#pragma unroll
            for (int i = 0; i < 4; ++i) a[i] = *(const float4*)&As[ty * 4 + i][kk];
#pragma unroll
            for (int j = 0; j < 4; ++j) b[j] = *(const float4*)&Bs[tx * 4 + j][kk];
#pragma unroll
            for (int i = 0; i < 4; ++i)
#pragma unroll
                for (int j = 0; j < 4; ++j)
                    acc[i][j] += a[i].x * b[j].x + a[i].y * b[j].y +
                                 a[i].z * b[j].z + a[i].w * b[j].w;
        }
        __syncthreads();
    }

    const int gn0 = n0 + tx * 4;
    const float4 bm = *(const float4*)&batt[gn0];
#pragma unroll
    for (int i = 0; i < 4; ++i) {
        const int gm = m0 + ty * 4 + i;
        if (gm >= NT) continue;
        float4 o;
        o.x = fmaxf(acc[i][0] + bm.x, 0.f);
        o.y = fmaxf(acc[i][1] + bm.y, 0.f);
        o.z = fmaxf(acc[i][2] + bm.z, 0.f);
        o.w = fmaxf(acc[i][3] + bm.w, 0.f);
        *(float4*)&tagH[(size_t)gm * KDIM + gn0] = o;
    }
}

// ---------------- Kernel B: per-row attention -----------------------------
// One block (256 thr = 4 waves) per batch row.
// scores s[m] = dot(tagH[tag_m], u); softmax; h = sum alpha_m * tagU[tag_m];
// writes h to ws, and r[b] = iv . (it - nit)  (init for kernel C's atomics).
__global__ __launch_bounds__(256) void attn_kernel(
    const int* __restrict__ x,         // [B,54]
    const float* __restrict__ userVecs,
    const float* __restrict__ itemVecs,
    const float* __restrict__ tagU,
    const float* __restrict__ tagI,
    const float* __restrict__ tagH,
    float* __restrict__ hbuf,          // [B,256]
    float* __restrict__ r)             // [B]
{
    const int b = blockIdx.x;
    const int tid = threadIdx.x;
    const int wave = tid >> 6, lane = tid & 63;

    __shared__ int   xs[XROW + 2];
    __shared__ float su[KDIM];
    __shared__ float sal[64];
    __shared__ float red[4];

    if (tid < XROW) xs[tid] = x[(size_t)b * XROW + tid];
    __syncthreads();
    const int x0 = xs[0], x1 = xs[1], x2 = xs[2], x3 = xs[3];

    su[tid] = userVecs[(size_t)x0 * KDIM + tid];
    __syncthreads();

    // scores: wave w handles m = w, w+4, ...
    for (int m = wave; m < MHIST; m += 4) {
        const int t = xs[4 + m];
        const float4 th = *(const float4*)&tagH[(size_t)t * KDIM + lane * 4];
        const float4 uu = *(const float4*)&su[lane * 4];
        float d = th.x * uu.x + th.y * uu.y + th.z * uu.z + th.w * uu.w;
#pragma unroll
        for (int off = 32; off >= 1; off >>= 1) d += __shfl_xor(d, off);
        if (lane == 0) sal[m] = d;
    }
    __syncthreads();

    // softmax over 50 (wave 0)
    if (wave == 0) {
        float v = (lane < MHIST) ? sal[lane] : -3.4e38f;
        float mx = v;
#pragma unroll
        for (int off = 32; off >= 1; off >>= 1) mx = fmaxf(mx, __shfl_xor(mx, off));
        float e = (lane < MHIST) ? expf(v - mx) : 0.f;
        float s = e;
#pragma unroll
        for (int off = 32; off >= 1; off >>= 1) s += __shfl_xor(s, off);
        if (lane < MHIST) sal[lane] = e / s;
    }
    __syncthreads();

    // h[k] = sum_m alpha[m] * tagU[tag_m][k]   (k = tid, coalesced gathers)
    float hacc = 0.f;
    for (int m = 0; m < MHIST; ++m) {
        const int t = xs[4 + m];
        hacc = fmaf(sal[m], tagU[(size_t)t * KDIM + tid], hacc);
    }
    hbuf[(size_t)b * KDIM + tid] = hacc;

    // r[b] = iv . (it - nit)
    const float iv  = itemVecs[(size_t)x1 * KDIM + tid];
    const float itv = tagI[(size_t)x2 * KDIM + tid];
    const float niv = tagI[(size_t)x3 * KDIM + tid];
    float part = iv * (itv - niv);
#pragma unroll
    for (int off = 32; off >= 1; off >>= 1) part += __shfl_xor(part, off);
    if (lane == 0) red[wave] = part;
    __syncthreads();
    if (tid == 0) r[b] = red[0] + red[1] + red[2] + red[3];
}

// ---------------- Kernel C: mix GEMM + fused final dot --------------------
// mix = relu(z @ W_map^T + b_map) with z[b] = [u, h, u-h, u*h] built on the
// fly from userVecs gathers + hbuf. Fused epilogue: atomicAdd partial
// mix . (ut - nut) into r[b]. Tile 64(b) x 64(j), K=1024, BK=32.
__global__ __launch_bounds__(256) void mix_kernel(
    const int* __restrict__ x,
    const float* __restrict__ userVecs,
    const float* __restrict__ tagU,
    const float* __restrict__ hbuf,
    const float* __restrict__ Wmap,   // [256,1024]
    const float* __restrict__ bmap,   // [256]
    float* __restrict__ r,
    int B)
{
    __shared__ float As[64][36];
    __shared__ float Bs[64][36];
    __shared__ int xr0[64], xr2[64], xr3[64];

    const int tid = threadIdx.x;
    const int tx = tid & 15, ty = tid >> 4;
    const int b0 = blockIdx.x * 64;
    const int n0 = blockIdx.y * 64;

    if (tid < 64) {
        const int gb = min(b0 + tid, B - 1);
        xr0[tid] = x[(size_t)gb * XROW + 0];
        xr2[tid] = x[(size_t)gb * XROW + 2];
        xr3[tid] = x[(size_t)gb * XROW + 3];
    }
    __syncthreads();

    float acc[4][4] = {};

    for (int k0 = 0; k0 < 4 * KDIM; k0 += 32) {
        const int seg = k0 >> 8;     // which of [u, h, u-h, u*h]
        const int kb  = k0 & 255;
#pragma unroll
        for (int p = 0; p < 2; ++p) {
            const int rr = (tid >> 3) + p * 32;
            const int c  = (tid & 7) * 4;
            const int gb = min(b0 + rr, B - 1);
            const int kk = kb + c;
            float4 av;
            if (seg == 0) {
                av = *(const float4*)&userVecs[(size_t)xr0[rr] * KDIM + kk];
            } else if (seg == 1) {
                av = *(const float4*)&hbuf[(size_t)gb * KDIM + kk];
            } else {
                const float4 uv = *(const float4*)&userVecs[(size_t)xr0[rr] * KDIM + kk];
                const float4 hv = *(const float4*)&hbuf[(size_t)gb * KDIM + kk];
                if (seg == 2)
                    av = make_float4(uv.x - hv.x, uv.y - hv.y, uv.z - hv.z, uv.w - hv.w);
                else
                    av = make_float4(uv.x * hv.x, uv.y * hv.y, uv.z * hv.z, uv.w * hv.w);
            }
            *(float4*)&As[rr][c] = av;
            const int gn = n0 + rr;  // < 256
            *(float4*)&Bs[rr][c] = *(const float4*)&Wmap[(size_t)gn * 1024 + k0 + c];
        }
        __syncthreads();
#pragma unroll
        for (int kk = 0; kk < 32; kk += 4) {
            float4 a[4], bb[4];
#pragma unroll
            for (int i = 0; i < 4; ++i) a[i] = *(const float4*)&As[ty * 4 + i][kk];
#pragma unroll
            for (int j = 0; j < 4; ++j) bb[j] = *(const float4*)&Bs[tx * 4 + j][kk];
#pragma unroll
            for (int i = 0; i < 4; ++i)
#pragma unroll
                for (int j = 0; j < 4; ++j)
                    acc[i][j] += a[i].x * bb[j].x + a[i].y * bb[j].y +
                                 a[i].z * bb[j].z + a[i].w * bb[j].w;
        }
        __syncthreads();
    }

    // epilogue: mix = relu(acc + b_map); partial r += mix . (ut - nut)
    const int gn0 = n0 + tx * 4;
    const float4 bm = *(const float4*)&bmap[gn0];
#pragma unroll
    for (int i = 0; i < 4; ++i) {
        const int gb = b0 + ty * 4 + i;
        const int row = ty * 4 + i;
        const float4 ut  = *(const float4*)&tagU[(size_t)xr2[row] * KDIM + gn0];
        const float4 nut = *(const float4*)&tagU[(size_t)xr3[row] * KDIM + gn0];
        float p = fmaxf(acc[i][0] + bm.x, 0.f) * (ut.x - nut.x)
                + fmaxf(acc[i][1] + bm.y, 0.f) * (ut.y - nut.y)
                + fmaxf(acc[i][2] + bm.z, 0.f) * (ut.z - nut.z)
                + fmaxf(acc[i][3] + bm.w, 0.f) * (ut.w - nut.w);
#pragma unroll
        for (int off = 8; off >= 1; off >>= 1) p += __shfl_xor(p, off);
        if (tx == 0 && gb < B) atomicAdd(&r[gb], p);
    }
}

extern "C" void kernel_launch(void* const* d_in, const int* in_sizes, int n_in,
                              void* d_out, int out_size, void* d_ws, size_t ws_size,
                              hipStream_t stream)
{
    const int*   x        = (const int*)d_in[0];
    const float* userVecs = (const float*)d_in[1];
    const float* itemVecs = (const float*)d_in[2];
    const float* tagU     = (const float*)d_in[3];
    const float* tagI     = (const float*)d_in[4];
    const float* Watt     = (const float*)d_in[5];
    const float* batt     = (const float*)d_in[6];
    const float* Wmap     = (const float*)d_in[7];
    const float* bmap     = (const float*)d_in[8];

    const int B  = in_sizes[0] / XROW;       // 16384
    const int NT = in_sizes[3] / KDIM;       // 50000

    // workspace: tagH [NT,256] f32 (51.2MB) + hbuf [B,256] f32 (16.8MB)
    float* tagH = (float*)d_ws;
    float* hbuf = tagH + (size_t)NT * KDIM;
    float* r    = (float*)d_out;

    dim3 gA((NT + 63) / 64, KDIM / 64);
    tagh_kernel<<<gA, 256, 0, stream>>>(tagU, Watt, batt, tagH, NT);

    attn_kernel<<<B, 256, 0, stream>>>(x, userVecs, itemVecs, tagU, tagI,
                                       tagH, hbuf, r);

    dim3 gC(B / 64, KDIM / 64);
    mix_kernel<<<gC, 256, 0, stream>>>(x, userVecs, tagU, hbuf, Wmap, bmap, r, B);
}

// Round 2
// 255.571 us; speedup vs baseline: 2.4334x; 2.4334x over previous
//
#include <hip/hip_runtime.h>

// AttentionPITF: B=16384, K=256, M=50.
// tagH precompute + mix GEMM now on bf16 MFMA (m97 structure: 128x128 tile,
// BK=32, global_load_lds width 16, 16x16x32 bf16 fragments).
// W_map folded: z@W^T = u@(W1+W3)^T + h@(W2-W3)^T + (u*h)@W4^T  (K 1024->768).

#define KDIM 256
#define MHIST 50
#define XROW 54
#define KFOLD 768

typedef __attribute__((ext_vector_type(8))) short bf16x8;
typedef __attribute__((ext_vector_type(4))) float f32x4;

__device__ __forceinline__ unsigned short f2bf(float f) {
    union { float f; unsigned int i; } v; v.f = f;
    unsigned int x = v.i;
    x += 0x7fffu + ((x >> 16) & 1u);          // RNE
    return (unsigned short)(x >> 16);
}
__device__ __forceinline__ float bf2f(unsigned short u) {
    union { unsigned int i; float f; } v; v.i = ((unsigned int)u) << 16;
    return v.f;
}

#define GLOAD16(g, l)                                                        \
    __builtin_amdgcn_global_load_lds(                                        \
        (const __attribute__((address_space(1))) void*)(g),                  \
        (__attribute__((address_space(3))) void*)(l), 16, 0, 0)

__device__ __forceinline__ f32x4 mfma16(bf16x8 a, bf16x8 b, f32x4 c) {
    return __builtin_amdgcn_mfma_f32_16x16x32_bf16(a, b, c, 0, 0, 0);
}

// ---------------- prep: f32 -> bf16 casts --------------------------------
__global__ __launch_bounds__(256) void cvt_kernel(
    const float* __restrict__ src, unsigned short* __restrict__ dst, int n4)
{
    int i = blockIdx.x * 256 + threadIdx.x;
    if (i >= n4) return;
    float4 v = ((const float4*)src)[i];
    ushort4 o;
    o.x = f2bf(v.x); o.y = f2bf(v.y); o.z = f2bf(v.z); o.w = f2bf(v.w);
    ((ushort4*)dst)[i] = o;
}

// Wfold[j][0:256]=W1+W3, [256:512]=W2-W3, [512:768]=W4  (from W_map[j][1024])
__global__ __launch_bounds__(256) void fold_kernel(
    const float* __restrict__ Wmap, unsigned short* __restrict__ Wf)
{
    int idx = blockIdx.x * 256 + threadIdx.x;   // < 256*768
    int j = idx / KFOLD, c = idx % KFOLD;
    int seg = c >> 8, k = c & 255;
    const float* row = Wmap + (size_t)j * 1024;
    float f;
    if (seg == 0)      f = row[k]       + row[512 + k];
    else if (seg == 1) f = row[256 + k] - row[512 + k];
    else               f = row[768 + k];
    Wf[idx] = f2bf(f);
}

// ---------------- Kernel A: tagH = relu(tagU @ W_att^T + b_att), bf16 MFMA
__global__ __launch_bounds__(256) void tagh_mfma_kernel(
    const unsigned short* __restrict__ Ab,   // tagU bf16 [NT][256]
    const unsigned short* __restrict__ Bb,   // W_att bf16 [256][256]
    const float* __restrict__ batt,
    unsigned short* __restrict__ Hb,         // tagH bf16 [NT][256]
    int NT)
{
    __shared__ unsigned short As[128 * 32];
    __shared__ unsigned short Bs[128 * 32];
    const int tid = threadIdx.x;
    const int lane = tid & 63, wave = tid >> 6;
    const int wr = wave >> 1, wc = wave & 1;
    const int m0 = blockIdx.x * 128, n0 = blockIdx.y * 128;

    f32x4 acc[4][4] = {};

    for (int k0 = 0; k0 < KDIM; k0 += 32) {
#pragma unroll
        for (int p = 0; p < 2; ++p) {
            int s = tid + p * 256;
            int row = s >> 2, ch = s & 3;
            int gm = m0 + row; if (gm >= NT) gm = NT - 1;
            GLOAD16(Ab + ((size_t)gm * KDIM + k0 + ch * 8), As + s * 8);
            GLOAD16(Bb + ((size_t)(n0 + row) * KDIM + k0 + ch * 8), Bs + s * 8);
        }
        __syncthreads();
        bf16x8 af[4], bg[4];
#pragma unroll
        for (int m = 0; m < 4; ++m) {
            int ar = wr * 64 + m * 16 + (lane & 15);
            af[m] = *(const bf16x8*)&As[ar * 32 + (lane >> 4) * 8];
        }
#pragma unroll
        for (int n = 0; n < 4; ++n) {
            int br = wc * 64 + n * 16 + (lane & 15);
            bg[n] = *(const bf16x8*)&Bs[br * 32 + (lane >> 4) * 8];
        }
#pragma unroll
        for (int m = 0; m < 4; ++m)
#pragma unroll
            for (int n = 0; n < 4; ++n)
                acc[m][n] = mfma16(af[m], bg[n], acc[m][n]);
        __syncthreads();
    }

#pragma unroll
    for (int n = 0; n < 4; ++n) {
        int col = n0 + wc * 64 + n * 16 + (lane & 15);
        float bias = batt[col];
#pragma unroll
        for (int m = 0; m < 4; ++m)
#pragma unroll
            for (int r = 0; r < 4; ++r) {
                int grow = m0 + wr * 64 + m * 16 + (lane >> 4) * 4 + r;
                if (grow < NT)
                    Hb[(size_t)grow * KDIM + col] =
                        f2bf(fmaxf(acc[m][n][r] + bias, 0.f));
            }
    }
}

// ---------------- Kernel B: per-row attention, bf16 gathers ---------------
__global__ __launch_bounds__(256) void attn_kernel(
    const int* __restrict__ x,
    const float* __restrict__ userVecs,
    const float* __restrict__ itemVecs,
    const float* __restrict__ tagI,
    const unsigned short* __restrict__ tagUb,
    const unsigned short* __restrict__ tagHb,
    unsigned short* __restrict__ zA,          // [B][768] bf16: u, h, u*h
    float* __restrict__ r)
{
    const int b = blockIdx.x;
    const int tid = threadIdx.x;
    const int wave = tid >> 6, lane = tid & 63;

    __shared__ int   xs[XROW];
    __shared__ float su[KDIM];
    __shared__ float sal[64];
    __shared__ float red[4];

    if (tid < XROW) xs[tid] = x[(size_t)b * XROW + tid];
    __syncthreads();
    su[tid] = userVecs[(size_t)xs[0] * KDIM + tid];
    __syncthreads();

    // scores
    for (int m = wave; m < MHIST; m += 4) {
        const int t = xs[4 + m];
        ushort4 th = *(const ushort4*)&tagHb[(size_t)t * KDIM + lane * 4];
        float4 uu = *(const float4*)&su[lane * 4];
        float d = bf2f(th.x) * uu.x + bf2f(th.y) * uu.y +
                  bf2f(th.z) * uu.z + bf2f(th.w) * uu.w;
#pragma unroll
        for (int off = 32; off >= 1; off >>= 1) d += __shfl_xor(d, off);
        if (lane == 0) sal[m] = d;
    }
    __syncthreads();

    if (wave == 0) {
        float v = (lane < MHIST) ? sal[lane] : -3.4e38f;
        float mx = v;
#pragma unroll
        for (int off = 32; off >= 1; off >>= 1) mx = fmaxf(mx, __shfl_xor(mx, off));
        float e = (lane < MHIST) ? expf(v - mx) : 0.f;
        float s = e;
#pragma unroll
        for (int off = 32; off >= 1; off >>= 1) s += __shfl_xor(s, off);
        if (lane < MHIST) sal[lane] = e / s;
    }
    __syncthreads();

    float hacc = 0.f;
    for (int m = 0; m < MHIST; ++m) {
        const int t = xs[4 + m];
        hacc = fmaf(sal[m], bf2f(tagUb[(size_t)t * KDIM + tid]), hacc);
    }
    const float u = su[tid];
    const size_t zb = (size_t)b * KFOLD;
    zA[zb + tid]       = f2bf(u);
    zA[zb + 256 + tid] = f2bf(hacc);
    zA[zb + 512 + tid] = f2bf(u * hacc);

    // r[b] = iv . (it - nit)   (all f32)
    const float iv  = itemVecs[(size_t)xs[1] * KDIM + tid];
    const float itv = tagI[(size_t)xs[2] * KDIM + tid];
    const float niv = tagI[(size_t)xs[3] * KDIM + tid];
    float part = iv * (itv - niv);
#pragma unroll
    for (int off = 32; off >= 1; off >>= 1) part += __shfl_xor(part, off);
    if (lane == 0) red[wave] = part;
    __syncthreads();
    if (tid == 0) r[b] = red[0] + red[1] + red[2] + red[3];
}

// ---------------- Kernel C: mix GEMM (bf16 MFMA) + fused dot --------------
__global__ __launch_bounds__(256) void mix_mfma_kernel(
    const unsigned short* __restrict__ Zb,   // [B][768] bf16
    const unsigned short* __restrict__ Wf,   // [256][768] bf16
    const float* __restrict__ bmap,
    const int* __restrict__ x,
    const float* __restrict__ tagU,          // f32, for ut/nut epilogue
    float* __restrict__ r,
    int Bn)
{
    __shared__ unsigned short As[128 * 32];
    __shared__ unsigned short Bs[128 * 32];
    __shared__ int xr2s[128], xr3s[128];

    const int tid = threadIdx.x;
    const int lane = tid & 63, wave = tid >> 6;
    const int wr = wave >> 1, wc = wave & 1;
    const int b0 = blockIdx.x * 128, n0 = blockIdx.y * 128;

    if (tid < 128) {
        int gb = b0 + tid;
        xr2s[tid] = x[(size_t)gb * XROW + 2];
        xr3s[tid] = x[(size_t)gb * XROW + 3];
    }

    f32x4 acc[4][4] = {};

    for (int k0 = 0; k0 < KFOLD; k0 += 32) {
#pragma unroll
        for (int p = 0; p < 2; ++p) {
            int s = tid + p * 256;
            int row = s >> 2, ch = s & 3;
            GLOAD16(Zb + ((size_t)(b0 + row) * KFOLD + k0 + ch * 8), As + s * 8);
            GLOAD16(Wf + ((size_t)(n0 + row) * KFOLD + k0 + ch * 8), Bs + s * 8);
        }
        __syncthreads();
        bf16x8 af[4], bg[4];
#pragma unroll
        for (int m = 0; m < 4; ++m) {
            int ar = wr * 64 + m * 16 + (lane & 15);
            af[m] = *(const bf16x8*)&As[ar * 32 + (lane >> 4) * 8];
        }
#pragma unroll
        for (int n = 0; n < 4; ++n) {
            int br = wc * 64 + n * 16 + (lane & 15);
            bg[n] = *(const bf16x8*)&Bs[br * 32 + (lane >> 4) * 8];
        }
#pragma unroll
        for (int m = 0; m < 4; ++m)
#pragma unroll
            for (int n = 0; n < 4; ++n)
                acc[m][n] = mfma16(af[m], bg[n], acc[m][n]);
        __syncthreads();
    }

    // epilogue: mix = relu(acc+bias); p = sum_cols mix*(ut-nut); atomic into r
    int   cols[4];
    float bias[4];
#pragma unroll
    for (int n = 0; n < 4; ++n) {
        cols[n] = n0 + wc * 64 + n * 16 + (lane & 15);
        bias[n] = bmap[cols[n]];
    }
#pragma unroll
    for (int m = 0; m < 4; ++m)
#pragma unroll
        for (int rr = 0; rr < 4; ++rr) {
            int rl = wr * 64 + m * 16 + (lane >> 4) * 4 + rr;
            const float* utp = tagU + (size_t)xr2s[rl] * KDIM;
            const float* ntp = tagU + (size_t)xr3s[rl] * KDIM;
            float p = 0.f;
#pragma unroll
            for (int n = 0; n < 4; ++n) {
                float mixv = fmaxf(acc[m][n][rr] + bias[n], 0.f);
                p += mixv * (utp[cols[n]] - ntp[cols[n]]);
            }
            p += __shfl_xor(p, 1);
            p += __shfl_xor(p, 2);
            p += __shfl_xor(p, 4);
            p += __shfl_xor(p, 8);
            if ((lane & 15) == 0) atomicAdd(&r[b0 + rl], p);
        }
}

extern "C" void kernel_launch(void* const* d_in, const int* in_sizes, int n_in,
                              void* d_out, int out_size, void* d_ws, size_t ws_size,
                              hipStream_t stream)
{
    const int*   x        = (const int*)d_in[0];
    const float* userVecs = (const float*)d_in[1];
    const float* itemVecs = (const float*)d_in[2];
    const float* tagU     = (const float*)d_in[3];
    const float* tagI     = (const float*)d_in[4];
    const float* Watt     = (const float*)d_in[5];
    const float* batt     = (const float*)d_in[6];
    const float* Wmap     = (const float*)d_in[7];
    const float* bmap     = (const float*)d_in[8];

    const int B  = in_sizes[0] / XROW;       // 16384
    const int NT = in_sizes[3] / KDIM;       // 50000

    // ws layout (ushort elements):
    unsigned short* tagUb  = (unsigned short*)d_ws;               // NT*256
    unsigned short* tagHb  = tagUb + (size_t)NT * KDIM;           // NT*256
    unsigned short* Wattb  = tagHb + (size_t)NT * KDIM;           // 256*256
    unsigned short* Wfoldb = Wattb + KDIM * KDIM;                 // 256*768
    unsigned short* zA     = Wfoldb + KDIM * KFOLD;               // B*768
    float* r = (float*)d_out;

    cvt_kernel<<<(NT * 64 + 255) / 256, 256, 0, stream>>>(tagU, tagUb, NT * 64);
    cvt_kernel<<<(KDIM * KDIM / 4 + 255) / 256, 256, 0, stream>>>(Watt, Wattb,
                                                                  KDIM * KDIM / 4);
    fold_kernel<<<KDIM * KFOLD / 256, 256, 0, stream>>>(Wmap, Wfoldb);

    dim3 gA((NT + 127) / 128, 2);
    tagh_mfma_kernel<<<gA, 256, 0, stream>>>(tagUb, Wattb, batt, tagHb, NT);

    attn_kernel<<<B, 256, 0, stream>>>(x, userVecs, itemVecs, tagI,
                                       tagUb, tagHb, zA, r);

    dim3 gC(B / 128, 2);
    mix_mfma_kernel<<<gC, 256, 0, stream>>>(zA, Wfoldb, bmap, x, tagU, r, B);
}

// Round 3
// 193.726 us; speedup vs baseline: 3.2102x; 1.3192x over previous
//
#include <hip/hip_runtime.h>

// AttentionPITF: B=16384, K=256, M=50.
// Round 3: attn restructured to one WAVE per row (was one block/row with 4
// barriers). 4 independent rows per block, no __syncthreads, x-row and alpha
// broadcast via __shfl. GEMMs unchanged (bf16 MFMA, m97 structure).

#define KDIM 256
#define MHIST 50
#define XROW 54
#define KFOLD 768

typedef __attribute__((ext_vector_type(8))) short bf16x8;
typedef __attribute__((ext_vector_type(4))) float f32x4;

__device__ __forceinline__ unsigned short f2bf(float f) {
    union { float f; unsigned int i; } v; v.f = f;
    unsigned int x = v.i;
    x += 0x7fffu + ((x >> 16) & 1u);          // RNE
    return (unsigned short)(x >> 16);
}
__device__ __forceinline__ float bf2f(unsigned short u) {
    union { unsigned int i; float f; } v; v.i = ((unsigned int)u) << 16;
    return v.f;
}

#define GLOAD16(g, l)                                                        \
    __builtin_amdgcn_global_load_lds(                                        \
        (const __attribute__((address_space(1))) void*)(g),                  \
        (__attribute__((address_space(3))) void*)(l), 16, 0, 0)

__device__ __forceinline__ f32x4 mfma16(bf16x8 a, bf16x8 b, f32x4 c) {
    return __builtin_amdgcn_mfma_f32_16x16x32_bf16(a, b, c, 0, 0, 0);
}

// ---------------- prep: f32 -> bf16 casts --------------------------------
__global__ __launch_bounds__(256) void cvt_kernel(
    const float* __restrict__ src, unsigned short* __restrict__ dst, int n4)
{
    int i = blockIdx.x * 256 + threadIdx.x;
    if (i >= n4) return;
    float4 v = ((const float4*)src)[i];
    ushort4 o;
    o.x = f2bf(v.x); o.y = f2bf(v.y); o.z = f2bf(v.z); o.w = f2bf(v.w);
    ((ushort4*)dst)[i] = o;
}

// Wfold[j][0:256]=W1+W3, [256:512]=W2-W3, [512:768]=W4  (from W_map[j][1024])
__global__ __launch_bounds__(256) void fold_kernel(
    const float* __restrict__ Wmap, unsigned short* __restrict__ Wf)
{
    int idx = blockIdx.x * 256 + threadIdx.x;   // < 256*768
    int j = idx / KFOLD, c = idx % KFOLD;
    int seg = c >> 8, k = c & 255;
    const float* row = Wmap + (size_t)j * 1024;
    float f;
    if (seg == 0)      f = row[k]       + row[512 + k];
    else if (seg == 1) f = row[256 + k] - row[512 + k];
    else               f = row[768 + k];
    Wf[idx] = f2bf(f);
}

// ---------------- Kernel A: tagH = relu(tagU @ W_att^T + b_att), bf16 MFMA
__global__ __launch_bounds__(256) void tagh_mfma_kernel(
    const unsigned short* __restrict__ Ab,   // tagU bf16 [NT][256]
    const unsigned short* __restrict__ Bb,   // W_att bf16 [256][256]
    const float* __restrict__ batt,
    unsigned short* __restrict__ Hb,         // tagH bf16 [NT][256]
    int NT)
{
    __shared__ unsigned short As[128 * 32];
    __shared__ unsigned short Bs[128 * 32];
    const int tid = threadIdx.x;
    const int lane = tid & 63, wave = tid >> 6;
    const int wr = wave >> 1, wc = wave & 1;
    const int m0 = blockIdx.x * 128, n0 = blockIdx.y * 128;

    f32x4 acc[4][4] = {};

    for (int k0 = 0; k0 < KDIM; k0 += 32) {
#pragma unroll
        for (int p = 0; p < 2; ++p) {
            int s = tid + p * 256;
            int row = s >> 2, ch = s & 3;
            int gm = m0 + row; if (gm >= NT) gm = NT - 1;
            GLOAD16(Ab + ((size_t)gm * KDIM + k0 + ch * 8), As + s * 8);
            GLOAD16(Bb + ((size_t)(n0 + row) * KDIM + k0 + ch * 8), Bs + s * 8);
        }
        __syncthreads();
        bf16x8 af[4], bg[4];
#pragma unroll
        for (int m = 0; m < 4; ++m) {
            int ar = wr * 64 + m * 16 + (lane & 15);
            af[m] = *(const bf16x8*)&As[ar * 32 + (lane >> 4) * 8];
        }
#pragma unroll
        for (int n = 0; n < 4; ++n) {
            int br = wc * 64 + n * 16 + (lane & 15);
            bg[n] = *(const bf16x8*)&Bs[br * 32 + (lane >> 4) * 8];
        }
#pragma unroll
        for (int m = 0; m < 4; ++m)
#pragma unroll
            for (int n = 0; n < 4; ++n)
                acc[m][n] = mfma16(af[m], bg[n], acc[m][n]);
        __syncthreads();
    }

#pragma unroll
    for (int n = 0; n < 4; ++n) {
        int col = n0 + wc * 64 + n * 16 + (lane & 15);
        float bias = batt[col];
#pragma unroll
        for (int m = 0; m < 4; ++m)
#pragma unroll
            for (int r = 0; r < 4; ++r) {
                int grow = m0 + wr * 64 + m * 16 + (lane >> 4) * 4 + r;
                if (grow < NT)
                    Hb[(size_t)grow * KDIM + col] =
                        f2bf(fmaxf(acc[m][n][r] + bias, 0.f));
            }
    }
}

// ---------------- Kernel B: per-row attention, one wave per row -----------
// 4 waves/block, wave w owns row b = blockIdx.x*4+w. No __syncthreads.
// x row + alpha broadcast via __shfl; LDS only for the 50 scores per wave.
__global__ __launch_bounds__(256) void attn_kernel(
    const int* __restrict__ x,
    const float* __restrict__ userVecs,
    const float* __restrict__ itemVecs,
    const float* __restrict__ tagI,
    const unsigned short* __restrict__ tagUb,
    const unsigned short* __restrict__ tagHb,
    unsigned short* __restrict__ zA,          // [B][768] bf16: u, h, u*h
    float* __restrict__ r)
{
    const int tid  = threadIdx.x;
    const int wave = tid >> 6, lane = tid & 63;
    const int b    = blockIdx.x * 4 + wave;

    __shared__ float sal[4][64];

    // x row into registers: lane l holds x[b][min(l,53)], broadcast via shfl
    const int xv = x[(size_t)b * XROW + (lane < XROW ? lane : XROW - 1)];
    const int x0 = __shfl(xv, 0), x1 = __shfl(xv, 1);
    const int x2 = __shfl(xv, 2), x3 = __shfl(xv, 3);

    // u in registers: lane holds elems 4*lane..4*lane+3
    const float4 u4 = *(const float4*)&userVecs[(size_t)x0 * KDIM + lane * 4];

    // scores: s[m] = dot(tagH[t_m], u), 2 per iteration for ILP
    for (int m = 0; m < MHIST; m += 2) {
        const int t0 = __shfl(xv, 4 + m);
        const int t1 = __shfl(xv, 5 + m);
        const ushort4 a0 = *(const ushort4*)&tagHb[(size_t)t0 * KDIM + lane * 4];
        const ushort4 a1 = *(const ushort4*)&tagHb[(size_t)t1 * KDIM + lane * 4];
        float d0 = bf2f(a0.x) * u4.x + bf2f(a0.y) * u4.y +
                   bf2f(a0.z) * u4.z + bf2f(a0.w) * u4.w;
        float d1 = bf2f(a1.x) * u4.x + bf2f(a1.y) * u4.y +
                   bf2f(a1.z) * u4.z + bf2f(a1.w) * u4.w;
#pragma unroll
        for (int off = 32; off >= 1; off >>= 1) {
            d0 += __shfl_xor(d0, off);
            d1 += __shfl_xor(d1, off);
        }
        if (lane == 0) { sal[wave][m] = d0; sal[wave][m + 1] = d1; }
    }

    // softmax over 50 (within wave; LDS written/read by same wave)
    float v = (lane < MHIST) ? sal[wave][lane] : -3.4e38f;
    float mx = v;
#pragma unroll
    for (int off = 32; off >= 1; off >>= 1) mx = fmaxf(mx, __shfl_xor(mx, off));
    float e = (lane < MHIST) ? expf(v - mx) : 0.f;
    float s = e;
#pragma unroll
    for (int off = 32; off >= 1; off >>= 1) s += __shfl_xor(s, off);
    const float alpha = e / s;

    // h[k] = sum_m alpha_m * tagU[t_m][k]; lane holds 4 components
    float4 h4 = make_float4(0.f, 0.f, 0.f, 0.f);
    for (int m = 0; m < MHIST; ++m) {
        const int   t = __shfl(xv, 4 + m);
        const float a = __shfl(alpha, m);
        const ushort4 tv = *(const ushort4*)&tagUb[(size_t)t * KDIM + lane * 4];
        h4.x = fmaf(a, bf2f(tv.x), h4.x);
        h4.y = fmaf(a, bf2f(tv.y), h4.y);
        h4.z = fmaf(a, bf2f(tv.z), h4.z);
        h4.w = fmaf(a, bf2f(tv.w), h4.w);
    }

    // z = [u, h, u*h] bf16
    const size_t zb = (size_t)b * KFOLD + lane * 4;
    ushort4 o;
    o.x = f2bf(u4.x); o.y = f2bf(u4.y); o.z = f2bf(u4.z); o.w = f2bf(u4.w);
    *(ushort4*)&zA[zb] = o;
    o.x = f2bf(h4.x); o.y = f2bf(h4.y); o.z = f2bf(h4.z); o.w = f2bf(h4.w);
    *(ushort4*)&zA[zb + 256] = o;
    o.x = f2bf(u4.x * h4.x); o.y = f2bf(u4.y * h4.y);
    o.z = f2bf(u4.z * h4.z); o.w = f2bf(u4.w * h4.w);
    *(ushort4*)&zA[zb + 512] = o;

    // r[b] = iv . (it - nit)   (all f32)
    const float4 iv  = *(const float4*)&itemVecs[(size_t)x1 * KDIM + lane * 4];
    const float4 itv = *(const float4*)&tagI[(size_t)x2 * KDIM + lane * 4];
    const float4 niv = *(const float4*)&tagI[(size_t)x3 * KDIM + lane * 4];
    float part = iv.x * (itv.x - niv.x) + iv.y * (itv.y - niv.y) +
                 iv.z * (itv.z - niv.z) + iv.w * (itv.w - niv.w);
#pragma unroll
    for (int off = 32; off >= 1; off >>= 1) part += __shfl_xor(part, off);
    if (lane == 0) r[b] = part;
}

// ---------------- Kernel C: mix GEMM (bf16 MFMA) + fused dot --------------
__global__ __launch_bounds__(256) void mix_mfma_kernel(
    const unsigned short* __restrict__ Zb,   // [B][768] bf16
    const unsigned short* __restrict__ Wf,   // [256][768] bf16
    const float* __restrict__ bmap,
    const int* __restrict__ x,
    const float* __restrict__ tagU,          // f32, for ut/nut epilogue
    float* __restrict__ r,
    int Bn)
{
    __shared__ unsigned short As[128 * 32];
    __shared__ unsigned short Bs[128 * 32];
    __shared__ int xr2s[128], xr3s[128];

    const int tid = threadIdx.x;
    const int lane = tid & 63, wave = tid >> 6;
    const int wr = wave >> 1, wc = wave & 1;
    const int b0 = blockIdx.x * 128, n0 = blockIdx.y * 128;

    if (tid < 128) {
        int gb = b0 + tid;
        xr2s[tid] = x[(size_t)gb * XROW + 2];
        xr3s[tid] = x[(size_t)gb * XROW + 3];
    }

    f32x4 acc[4][4] = {};

    for (int k0 = 0; k0 < KFOLD; k0 += 32) {
#pragma unroll
        for (int p = 0; p < 2; ++p) {
            int s = tid + p * 256;
            int row = s >> 2, ch = s & 3;
            GLOAD16(Zb + ((size_t)(b0 + row) * KFOLD + k0 + ch * 8), As + s * 8);
            GLOAD16(Wf + ((size_t)(n0 + row) * KFOLD + k0 + ch * 8), Bs + s * 8);
        }
        __syncthreads();
        bf16x8 af[4], bg[4];
#pragma unroll
        for (int m = 0; m < 4; ++m) {
            int ar = wr * 64 + m * 16 + (lane & 15);
            af[m] = *(const bf16x8*)&As[ar * 32 + (lane >> 4) * 8];
        }
#pragma unroll
        for (int n = 0; n < 4; ++n) {
            int br = wc * 64 + n * 16 + (lane & 15);
            bg[n] = *(const bf16x8*)&Bs[br * 32 + (lane >> 4) * 8];
        }
#pragma unroll
        for (int m = 0; m < 4; ++m)
#pragma unroll
            for (int n = 0; n < 4; ++n)
                acc[m][n] = mfma16(af[m], bg[n], acc[m][n]);
        __syncthreads();
    }

    // epilogue: mix = relu(acc+bias); p = sum_cols mix*(ut-nut); atomic into r
    int   cols[4];
    float bias[4];
#pragma unroll
    for (int n = 0; n < 4; ++n) {
        cols[n] = n0 + wc * 64 + n * 16 + (lane & 15);
        bias[n] = bmap[cols[n]];
    }
#pragma unroll
    for (int m = 0; m < 4; ++m)
#pragma unroll
        for (int rr = 0; rr < 4; ++rr) {
            int rl = wr * 64 + m * 16 + (lane >> 4) * 4 + rr;
            const float* utp = tagU + (size_t)xr2s[rl] * KDIM;
            const float* ntp = tagU + (size_t)xr3s[rl] * KDIM;
            float p = 0.f;
#pragma unroll
            for (int n = 0; n < 4; ++n) {
                float mixv = fmaxf(acc[m][n][rr] + bias[n], 0.f);
                p += mixv * (utp[cols[n]] - ntp[cols[n]]);
            }
            p += __shfl_xor(p, 1);
            p += __shfl_xor(p, 2);
            p += __shfl_xor(p, 4);
            p += __shfl_xor(p, 8);
            if ((lane & 15) == 0) atomicAdd(&r[b0 + rl], p);
        }
}

extern "C" void kernel_launch(void* const* d_in, const int* in_sizes, int n_in,
                              void* d_out, int out_size, void* d_ws, size_t ws_size,
                              hipStream_t stream)
{
    const int*   x        = (const int*)d_in[0];
    const float* userVecs = (const float*)d_in[1];
    const float* itemVecs = (const float*)d_in[2];
    const float* tagU     = (const float*)d_in[3];
    const float* tagI     = (const float*)d_in[4];
    const float* Watt     = (const float*)d_in[5];
    const float* batt     = (const float*)d_in[6];
    const float* Wmap     = (const float*)d_in[7];
    const float* bmap     = (const float*)d_in[8];

    const int B  = in_sizes[0] / XROW;       // 16384
    const int NT = in_sizes[3] / KDIM;       // 50000

    // ws layout (ushort elements):
    unsigned short* tagUb  = (unsigned short*)d_ws;               // NT*256
    unsigned short* tagHb  = tagUb + (size_t)NT * KDIM;           // NT*256
    unsigned short* Wattb  = tagHb + (size_t)NT * KDIM;           // 256*256
    unsigned short* Wfoldb = Wattb + KDIM * KDIM;                 // 256*768
    unsigned short* zA     = Wfoldb + KDIM * KFOLD;               // B*768
    float* r = (float*)d_out;

    cvt_kernel<<<(NT * 64 + 255) / 256, 256, 0, stream>>>(tagU, tagUb, NT * 64);
    cvt_kernel<<<(KDIM * KDIM / 4 + 255) / 256, 256, 0, stream>>>(Watt, Wattb,
                                                                  KDIM * KDIM / 4);
    fold_kernel<<<KDIM * KFOLD / 256, 256, 0, stream>>>(Wmap, Wfoldb);

    dim3 gA((NT + 127) / 128, 2);
    tagh_mfma_kernel<<<gA, 256, 0, stream>>>(tagUb, Wattb, batt, tagHb, NT);

    attn_kernel<<<B / 4, 256, 0, stream>>>(x, userVecs, itemVecs, tagI,
                                           tagUb, tagHb, zA, r);

    dim3 gC(B / 128, 2);
    mix_mfma_kernel<<<gC, 256, 0, stream>>>(zA, Wfoldb, bmap, x, tagU, r, B);
}